// Round 3
// baseline (458.618 us; speedup 1.0000x reference)
//
#include <hip/hip_runtime.h>
#include <stdint.h>

#define BATCH 8
#define SEQ 2048
#define DIM 1024
#define MTOT (BATCH * SEQ)   // 16384
#define NM 16                // seq chunks per batch (128 t each) = m-tiles/batch
#define NTILE 8              // n-tiles

typedef __attribute__((ext_vector_type(8))) short short8;
typedef __attribute__((ext_vector_type(8))) unsigned short ushort8;
typedef __attribute__((ext_vector_type(4))) float floatx4;

// ---------- helpers ----------

__device__ __forceinline__ unsigned short f2bf(float f) {
  union { float f; unsigned u; } c; c.f = f;
  unsigned u = c.u;
  return (unsigned short)((u + 0x7FFFu + ((u >> 16) & 1u)) >> 16);
}
__device__ __forceinline__ float bf2f(unsigned short h) {
  union { unsigned u; float f; } c; c.u = ((unsigned)h) << 16;
  return c.f;
}

__device__ __forceinline__ void gll16(const void* g, void* l) {
  __builtin_amdgcn_global_load_lds(
      (__attribute__((address_space(1))) void*)(uintptr_t)g,
      (__attribute__((address_space(3))) void*)(uintptr_t)l,
      16, 0, 0);
}

// pack hi16 of two fp32 (RTZ bf16): dst = (hi16(f1)<<16)|hi16(f0)
__device__ __forceinline__ unsigned pkbf(float f1, float f0) {
  return __builtin_amdgcn_perm(__builtin_bit_cast(unsigned, f1),
                               __builtin_bit_cast(unsigned, f0), 0x07060302u);
}

// ---------- cast B, W fp32->bf16 (RTNE) + zero flags/ticket ----------

#define MN8 (DIM * DIM / 8)  // 131072

__global__ __launch_bounds__(256) void castBW_kernel(
    const float* __restrict__ B, const float* __restrict__ W,
    unsigned short* __restrict__ Bb, unsigned short* __restrict__ Wb,
    unsigned* __restrict__ flags /* 1024 flags + 1 ticket */) {
  int i = blockIdx.x * 256 + threadIdx.x;
  if (blockIdx.x == 0) {
    for (int w = threadIdx.x; w < 1025; w += 256) flags[w] = 0u;
  }
  const float* src; unsigned short* dst; int li;
  if (i < MN8) { src = B; dst = Bb; li = i; }
  else         { src = W; dst = Wb; li = i - MN8; }
  const float4* s4 = (const float4*)src;
  float4 a = s4[2 * li], b = s4[2 * li + 1];
  uint4 o;
  o.x = (unsigned)f2bf(a.x) | ((unsigned)f2bf(a.y) << 16);
  o.y = (unsigned)f2bf(a.z) | ((unsigned)f2bf(a.w) << 16);
  o.z = (unsigned)f2bf(b.x) | ((unsigned)f2bf(b.y) << 16);
  o.w = (unsigned)f2bf(b.z) | ((unsigned)f2bf(b.w) << 16);
  ((uint4*)dst)[li] = o;
}

// ---------- GEMM1 fused with diagonal-scan epilogue ----------
// A = x fp32 [M x 1024], staged fp32 in LDS, converted to bf16 fragments.
// B = Bb bf16 [1024 x 1024]. Output h bf16 (in-place scanned).
// Tile 128x128 (m-tile == 128-step seq chunk of one batch), BK=64, 4 waves.
// Epilogue: local scan in LDS + aggregate publish + lookback carry + writeout.

__global__ __launch_bounds__(256) void gemm1_scan(
    const float* __restrict__ x, const unsigned short* __restrict__ Bb,
    const float* __restrict__ Adiag, unsigned short* __restrict__ h,
    float* __restrict__ aggbuf, unsigned* __restrict__ flags,
    unsigned* __restrict__ ticket) {
  __shared__ __align__(16) char smem[49152];  // sA fp32 32K | sB bf16 16K
  float* sAf = (float*)smem;
  unsigned short* sBu = (unsigned short*)(smem + 32768);
  __shared__ unsigned tkt;

  const int tid = threadIdx.x;
  const int wave = tid >> 6, lane = tid & 63;

  // ticket: tile order = schedule order (lookback liveness); ticket%8==b so
  // same-batch x-band stays on one XCD (heuristic L2 locality).
  if (tid == 0) tkt = atomicAdd(ticket, 1u);
  __syncthreads();
  const unsigned id = tkt;
  const int c = id >> 6;            // chunk 0..15 (ascending in schedule)
  const int b = id & 7;             // batch
  const int nt = (id >> 3) & 7;     // n-tile
  const int mt = b * NM + c;        // global m-tile 0..127
  const size_t m0 = (size_t)mt * 128;
  const int n0 = nt * 128;

  floatx4 acc[4][4] = {};

  // --- staging offsets ---
  // A (fp32): 8 rounds/wave, 4 rows/round, 16 lanes/row (16B blocks),
  // 16B-block XOR swizzle by (row&15).
  unsigned offA[8];
#pragma unroll
  for (int r = 0; r < 8; ++r) {
    int row = wave * 32 + r * 4 + (lane >> 4);
    int blk = (lane & 15) ^ (row & 15);
    offA[r] = (unsigned)(row * 4096 + blk * 16);  // bytes (row*1024 floats)
  }
  // B (bf16): 4 rounds/wave, 8 rows/round, 8 lanes/row, swizzle by (row&7).
  unsigned offB[4];
#pragma unroll
  for (int r = 0; r < 4; ++r) {
    int row = r * 32 + wave * 8 + (lane >> 3);
    int blk = (lane & 7) ^ ((lane >> 3) & 7);
    offB[r] = (unsigned)(row * 2048 + blk * 16);  // bytes (row*1024 bf16)
  }
  const char* baseA = (const char*)(x + m0 * 1024);
  const char* baseB = (const char*)(Bb + (size_t)n0 * 1024);

  const int fr = lane & 15;       // fragment row (m or n)
  const int kb = lane >> 4;       // 0..3
  const int wm = (wave & 1) * 64, wn = (wave >> 1) * 64;

  for (int kt = 0; kt < 1024; kt += 64) {
#pragma unroll
    for (int r = 0; r < 8; ++r)
      gll16(baseA + offA[r], smem + (wave * 32 + r * 4) * 256);
#pragma unroll
    for (int r = 0; r < 4; ++r)
      gll16(baseB + offB[r], (char*)sBu + (wave * 8 + r * 32) * 128);
    baseA += 256;  // 64 floats
    baseB += 128;  // 64 bf16
    asm volatile("s_waitcnt vmcnt(0)" ::: "memory");
    __syncthreads();
#pragma unroll
    for (int kk = 0; kk < 64; kk += 32) {
      short8 af[4], bfv[4];
#pragma unroll
      for (int i = 0; i < 4; ++i) {
        const float* pA = sAf + (wm + i * 16 + fr) * 64;
        int bb0 = (kk >> 2) + kb * 2;
        float4 lo = *(const float4*)(pA + ((bb0 ^ fr) << 2));
        float4 hi = *(const float4*)(pA + (((bb0 + 1) ^ fr) << 2));
        union { short8 s; uint4 u; } cv;
        cv.u.x = pkbf(lo.y, lo.x);
        cv.u.y = pkbf(lo.w, lo.z);
        cv.u.z = pkbf(hi.y, hi.x);
        cv.u.w = pkbf(hi.w, hi.z);
        af[i] = cv.s;
      }
#pragma unroll
      for (int jj = 0; jj < 4; ++jj)
        bfv[jj] = *(const short8*)(sBu + (wn + jj * 16 + fr) * 64 +
                                   ((((kk >> 3) + kb) ^ (fr & 7)) * 8));
#pragma unroll
      for (int i = 0; i < 4; ++i)
#pragma unroll
        for (int jj = 0; jj < 4; ++jj)
          acc[i][jj] = __builtin_amdgcn_mfma_f32_16x16x32_bf16(
              af[i], bfv[jj], acc[i][jj], 0, 0, 0);
    }
    __syncthreads();
  }

  // ---------- epilogue: u tile -> local scan -> carry -> h ----------
  unsigned short* sC = (unsigned short*)smem;       // [128][128] bf16 (32K)
  float* segsum = (float*)(smem + 32768);           // [2][128]
  float* aLs    = (float*)(smem + 32768 + 1024);    // a^64 per col
  float* l2as   = (float*)(smem + 32768 + 1536);    // log2(a) per col
  float* carryB = (float*)(smem + 32768 + 2048);    // carry-in per col

  // 1) store u tile (C/D map: col=lane&15, row=(lane>>4)*4+reg)
  const int col = lane & 15;
  const int row4 = (lane >> 4) * 4;
#pragma unroll
  for (int i = 0; i < 4; ++i)
#pragma unroll
    for (int jj = 0; jj < 4; ++jj)
#pragma unroll
      for (int r = 0; r < 4; ++r)
        sC[(wm + i * 16 + row4 + r) * 128 + wn + jj * 16 + col] =
            f2bf(acc[i][jj][r]);
  __syncthreads();

  // 2) per-column segment scans (2 segs x 64 t), fp32 accum, bf16 writeback
  {
    const int n = tid & 127, seg = tid >> 7;
    const float a = Adiag[n0 + n];
    float s = 0.f;
    int t0 = seg * 64;
#pragma unroll 8
    for (int t = 0; t < 64; ++t) {
      s = fmaf(a, s, bf2f(sC[(t0 + t) * 128 + n]));
      sC[(t0 + t) * 128 + n] = f2bf(s);
    }
    segsum[seg * 128 + n] = s;
    if (seg == 0) {
      float a2 = a * a, a4 = a2 * a2, a8 = a4 * a4, a16 = a8 * a8;
      float a32 = a16 * a16;
      aLs[n] = a32 * a32;
      l2as[n] = __builtin_amdgcn_logf(a);
    }
  }
  __syncthreads();

  // 3) publish chunk aggregate (h over full 128 steps, zero carry-in)
  if (tid < 128) {
    aggbuf[(size_t)mt * 1024 + n0 + tid] =
        segsum[128 + tid] + aLs[tid] * segsum[tid];
  }
  __syncthreads();
  if (tid == 0)
    __hip_atomic_store(&flags[mt * 8 + nt], 1u, __ATOMIC_RELEASE,
                       __HIP_MEMORY_SCOPE_AGENT);

  // 4) lookback: carry_in = sum_p agg_p * (a^128)^(c-1-p)
  if (tid < 128) {
    float aL128 = aLs[tid] * aLs[tid];
    float cb = 0.f;
    for (int p = 0; p < c; ++p) {
      const int fi = (b * NM + p) * 8 + nt;
      while (__hip_atomic_load(&flags[fi], __ATOMIC_ACQUIRE,
                               __HIP_MEMORY_SCOPE_AGENT) == 0u)
        __builtin_amdgcn_s_sleep(2);
      cb = fmaf(aL128, cb, aggbuf[(size_t)(b * NM + p) * 1024 + n0 + tid]);
    }
    carryB[tid] = cb;
  }
  __syncthreads();

  // 5) writeout h = local + a^(rr+1) * C_seg, coalesced 16B stores
  {
    const int nb = (lane & 15) * 8;  // thread's 8 columns (fixed across rows)
    const int seg = wave >> 1;       // rows wave*32.. => seg = wave>>1
    float cf[8], l2[8], a4v[8], apow[8];
#pragma unroll
    for (int j = 0; j < 8; ++j) {
      int n = nb + j;
      float cb = carryB[n];
      cf[j] = seg ? fmaf(aLs[n], cb, segsum[n]) : cb;
      l2[j] = l2as[n];
      float a = Adiag[n0 + n];
      float a2 = a * a;
      a4v[j] = a2 * a2;
    }
    const int rr0 = (wave & 1) * 32 + (lane >> 4);  // (row&63) at s=0
#pragma unroll
    for (int j = 0; j < 8; ++j)
      apow[j] = __builtin_amdgcn_exp2f(l2[j] * (float)(rr0 + 1));
    unsigned short* hout = h + (m0 + wave * 32) * 1024 + n0 + nb;
#pragma unroll
    for (int s = 0; s < 8; ++s) {
      int row = wave * 32 + s * 4 + (lane >> 4);
      ushort8 loc = *(const ushort8*)(sC + row * 128 + nb);
      ushort8 o;
#pragma unroll
      for (int j = 0; j < 8; ++j) {
        float v = fmaf(apow[j], cf[j], bf2f(loc[j]));
        o[j] = f2bf(v);
        apow[j] *= a4v[j];  // rows advance by 4 within segment
      }
      *(ushort8*)(hout + (size_t)(s * 4 + (lane >> 4)) * 1024) = o;
    }
  }
}

// ---------- GEMM2: y = h . W^T + bias (fp32 out) — round-2 structure ----------

__global__ __launch_bounds__(256) void gemm2(
    const unsigned short* __restrict__ A,  // h bf16 [M x 1024]
    const unsigned short* __restrict__ B,  // Wb bf16 [1024 x 1024]
    float* __restrict__ C, const float* __restrict__ bias) {
  __shared__ unsigned short smem[16384];  // sA 16K shorts? no: 8192+8192
  unsigned short* sA = smem;
  unsigned short* sB = smem + 8192;

  const int tid = threadIdx.x;
  const int wave = tid >> 6, lane = tid & 63;

  const int id = blockIdx.x;
  const int xcd = id & 7, j = id >> 3;
  const int mt = xcd * 16 + (j >> 3);
  const int nt = j & 7;
  const size_t m0 = (size_t)mt * 128;
  const int n0 = nt * 128;

  floatx4 acc[4][4] = {};

  const int srow = wave * 8 + (lane >> 3);
  const int scol = (((lane & 7) ^ ((lane >> 3) & 7)) * 8);
  const unsigned short* gA = A + (m0 + srow) * 1024 + scol;
  const unsigned short* gB = B + ((size_t)n0 + srow) * 1024 + scol;
  unsigned short* lA = sA + wave * 8 * 64;
  unsigned short* lB = sB + wave * 8 * 64;

  const int fr = lane & 15;
  const int frs = fr & 7;
  const int kb = lane >> 4;
  const int wm = (wave & 1) * 64, wn = (wave >> 1) * 64;

  for (int kt = 0; kt < 1024; kt += 64) {
#pragma unroll
    for (int r = 0; r < 4; ++r) {
      gll16(gA + (size_t)r * 32 * 1024 + kt, lA + r * 32 * 64);
      gll16(gB + (size_t)r * 32 * 1024 + kt, lB + r * 32 * 64);
    }
    asm volatile("s_waitcnt vmcnt(0)" ::: "memory");
    __syncthreads();
#pragma unroll
    for (int kk = 0; kk < 64; kk += 32) {
      short8 af[4], bfv[4];
#pragma unroll
      for (int i = 0; i < 4; ++i)
        af[i] = *(const short8*)(sA + (wm + i * 16 + fr) * 64 +
                                 ((((kk >> 3) + kb) ^ frs) * 8));
#pragma unroll
      for (int jj = 0; jj < 4; ++jj)
        bfv[jj] = *(const short8*)(sB + (wn + jj * 16 + fr) * 64 +
                                   ((((kk >> 3) + kb) ^ frs) * 8));
#pragma unroll
      for (int i = 0; i < 4; ++i)
#pragma unroll
        for (int jj = 0; jj < 4; ++jj)
          acc[i][jj] = __builtin_amdgcn_mfma_f32_16x16x32_bf16(
              af[i], bfv[jj], acc[i][jj], 0, 0, 0);
    }
    __syncthreads();
  }

  const int col = lane & 15;
  const int row4 = (lane >> 4) * 4;
#pragma unroll
  for (int i = 0; i < 4; ++i)
#pragma unroll
    for (int jj = 0; jj < 4; ++jj)
#pragma unroll
      for (int r = 0; r < 4; ++r) {
        size_t m = m0 + wm + i * 16 + row4 + r;
        int n = n0 + wn + jj * 16 + col;
        C[m * 1024 + n] = acc[i][jj][r] + bias[n];
      }
}

// ---------- launcher ----------

extern "C" void kernel_launch(void* const* d_in, const int* in_sizes, int n_in,
                              void* d_out, int out_size, void* d_ws,
                              size_t ws_size, hipStream_t stream) {
  const float* x    = (const float*)d_in[0];
  const float* A    = (const float*)d_in[1];
  const float* B    = (const float*)d_in[2];
  const float* W    = (const float*)d_in[3];
  const float* bias = (const float*)d_in[4];

  char* ws = (char*)d_ws;
  unsigned short* hbuf = (unsigned short*)ws;              // 32 MB
  unsigned short* Bb = (unsigned short*)(ws + 33554432);   //  2 MB
  unsigned short* Wb = (unsigned short*)(ws + 35651584);   //  2 MB
  float* aggbuf = (float*)(ws + 37748736);                 // 512 KB
  unsigned* flags = (unsigned*)(ws + 38273024);            // 1024 flags + ticket
  unsigned* ticket = flags + 1024;

  castBW_kernel<<<2 * MN8 / 256, 256, 0, stream>>>(B, W, Bb, Wb, flags);

  gemm1_scan<<<128 * NTILE, 256, 0, stream>>>(x, Bb, A, hbuf, aggbuf, flags,
                                              ticket);

  gemm2<<<128 * NTILE, 256, 0, stream>>>(hbuf, Wb, (float*)d_out, bias);
}

// Round 4
// 322.323 us; speedup vs baseline: 1.4229x; 1.4229x over previous
//
#include <hip/hip_runtime.h>
#include <stdint.h>

#define BATCH 8
#define SEQ 2048
#define DIM 1024
#define MTOT (BATCH * SEQ)   // 16384
#define SC_NCH 32            // scan chunks per batch
#define SC_LEN 64            // timesteps per chunk

typedef __attribute__((ext_vector_type(8))) short short8;
typedef __attribute__((ext_vector_type(8))) unsigned short ushort8;
typedef __attribute__((ext_vector_type(4))) float floatx4;

// ---------- helpers ----------

__device__ __forceinline__ unsigned short f2bf(float f) {
  union { float f; unsigned u; } c; c.f = f;
  unsigned u = c.u;
  return (unsigned short)((u + 0x7FFFu + ((u >> 16) & 1u)) >> 16);
}
__device__ __forceinline__ float bf2f(unsigned short h) {
  union { unsigned u; float f; } c; c.u = ((unsigned)h) << 16;
  return c.f;
}

__device__ __forceinline__ void gll16(const void* g, void* l) {
  __builtin_amdgcn_global_load_lds(
      (__attribute__((address_space(1))) void*)(uintptr_t)g,
      (__attribute__((address_space(3))) void*)(uintptr_t)l,
      16, 0, 0);
}

// pack hi16 of two fp32 (RTZ bf16): dst = (hi16(f1)<<16)|hi16(f0)
__device__ __forceinline__ unsigned pkbf(float f1, float f0) {
  return __builtin_amdgcn_perm(__builtin_bit_cast(unsigned, f1),
                               __builtin_bit_cast(unsigned, f0), 0x07060302u);
}

// ---------- cast B, W fp32->bf16 (RTNE) + zero scan flags ----------

#define MN8 (DIM * DIM / 8)  // 131072

__global__ __launch_bounds__(256) void castBW_kernel(
    const float* __restrict__ B, const float* __restrict__ W,
    unsigned short* __restrict__ Bb, unsigned short* __restrict__ Wb,
    unsigned* __restrict__ flags /* 256 */) {
  int i = blockIdx.x * 256 + threadIdx.x;
  if (blockIdx.x == 0 && threadIdx.x < 256) flags[threadIdx.x] = 0u;
  const float* src; unsigned short* dst; int li;
  if (i < MN8) { src = B; dst = Bb; li = i; }
  else         { src = W; dst = Wb; li = i - MN8; }
  const float4* s4 = (const float4*)src;
  float4 a = s4[2 * li], b = s4[2 * li + 1];
  uint4 o;
  o.x = (unsigned)f2bf(a.x) | ((unsigned)f2bf(a.y) << 16);
  o.y = (unsigned)f2bf(a.z) | ((unsigned)f2bf(a.w) << 16);
  o.z = (unsigned)f2bf(b.x) | ((unsigned)f2bf(b.y) << 16);
  o.w = (unsigned)f2bf(b.z) | ((unsigned)f2bf(b.w) << 16);
  ((uint4*)dst)[li] = o;
}

// ---------- GEMM1: u[m][n] = sum_d x[m][d] * B[n][d], fp32 A staged in LDS ----
// Round-2 block mapping (measured FETCH=ideal, 0 conflicts), plain epilogue.

__global__ __launch_bounds__(256) void gemm1(
    const float* __restrict__ x, const unsigned short* __restrict__ Bb,
    unsigned short* __restrict__ u) {
  __shared__ __align__(16) char smem[49152];  // sA fp32 32K | sB bf16 16K
  float* sAf = (float*)smem;
  unsigned short* sBu = (unsigned short*)(smem + 32768);

  const int tid = threadIdx.x;
  const int wave = tid >> 6, lane = tid & 63;

  // XCD-aware tile remap (round-2, measured-good)
  const int id = blockIdx.x;
  const int xcd = id & 7, j = id >> 3;
  const int mt = xcd * 16 + (j >> 3);
  const int nt = j & 7;
  const size_t m0 = (size_t)mt * 128;
  const int n0 = nt * 128;

  floatx4 acc[4][4] = {};

  // A (fp32): 8 rounds/wave, 4 rows/round, 16 lanes/row, 16B-block swizzle.
  unsigned offA[8];
#pragma unroll
  for (int r = 0; r < 8; ++r) {
    int row = wave * 32 + r * 4 + (lane >> 4);
    int blk = (lane & 15) ^ (row & 15);
    offA[r] = (unsigned)(row * 4096 + blk * 16);
  }
  // B (bf16): 4 rounds/wave, 8 rows/round, 8 lanes/row, swizzle by row&7.
  unsigned offB[4];
#pragma unroll
  for (int r = 0; r < 4; ++r) {
    int row = r * 32 + wave * 8 + (lane >> 3);
    int blk = (lane & 7) ^ ((lane >> 3) & 7);
    offB[r] = (unsigned)(row * 2048 + blk * 16);
  }
  const char* baseA = (const char*)(x + m0 * 1024);
  const char* baseB = (const char*)(Bb + (size_t)n0 * 1024);

  const int fr = lane & 15;
  const int kb = lane >> 4;
  const int wm = (wave & 1) * 64, wn = (wave >> 1) * 64;

  for (int kt = 0; kt < 1024; kt += 64) {
#pragma unroll
    for (int r = 0; r < 8; ++r)
      gll16(baseA + offA[r], smem + (wave * 32 + r * 4) * 256);
#pragma unroll
    for (int r = 0; r < 4; ++r)
      gll16(baseB + offB[r], (char*)sBu + (wave * 8 + r * 32) * 128);
    baseA += 256;
    baseB += 128;
    asm volatile("s_waitcnt vmcnt(0)" ::: "memory");
    __syncthreads();
#pragma unroll
    for (int kk = 0; kk < 64; kk += 32) {
      short8 af[4], bfv[4];
#pragma unroll
      for (int i = 0; i < 4; ++i) {
        const float* pA = sAf + (wm + i * 16 + fr) * 64;
        int bb0 = (kk >> 2) + kb * 2;
        float4 lo = *(const float4*)(pA + ((bb0 ^ fr) << 2));
        float4 hi = *(const float4*)(pA + (((bb0 + 1) ^ fr) << 2));
        union { short8 s; uint4 u; } cv;
        cv.u.x = pkbf(lo.y, lo.x);
        cv.u.y = pkbf(lo.w, lo.z);
        cv.u.z = pkbf(hi.y, hi.x);
        cv.u.w = pkbf(hi.w, hi.z);
        af[i] = cv.s;
      }
#pragma unroll
      for (int jj = 0; jj < 4; ++jj)
        bfv[jj] = *(const short8*)(sBu + (wn + jj * 16 + fr) * 64 +
                                   ((((kk >> 3) + kb) ^ (fr & 7)) * 8));
#pragma unroll
      for (int i = 0; i < 4; ++i)
#pragma unroll
        for (int jj = 0; jj < 4; ++jj)
          acc[i][jj] = __builtin_amdgcn_mfma_f32_16x16x32_bf16(
              af[i], bfv[jj], acc[i][jj], 0, 0, 0);
    }
    __syncthreads();
  }

  // bf16 LDS-bounce epilogue (round-2, coalesced 16B stores)
  const int col = lane & 15;
  const int row4 = (lane >> 4) * 4;
  unsigned short* sC = (unsigned short*)smem;  // 32 KB
#pragma unroll
  for (int i = 0; i < 4; ++i)
#pragma unroll
    for (int jj = 0; jj < 4; ++jj)
#pragma unroll
      for (int r = 0; r < 4; ++r)
        sC[(wm + i * 16 + row4 + r) * 128 + wn + jj * 16 + col] =
            f2bf(acc[i][jj][r]);
  __syncthreads();
#pragma unroll
  for (int s = 0; s < 8; ++s) {
    int row = wave * 32 + s * 4 + (lane >> 4);
    int c8 = (lane & 15) * 8;
    *(ushort8*)(u + (m0 + row) * (size_t)1024 + n0 + c8) =
        *(const ushort8*)(sC + row * 128 + c8);
  }
}

// ---------- single-kernel decoupled-lookback scan ----------
// u [8][2048][1024] bf16, in-place -> h. 256 blocks (1/CU), all co-resident.
// Block = (b, chunk of 64 t). Thread: 8 channels x 32 t held in registers.

__global__ __launch_bounds__(256) void scan_lb(
    unsigned short* __restrict__ u, const float* __restrict__ Adiag,
    float* __restrict__ aggbuf, unsigned* __restrict__ flags) {
  const int blk = blockIdx.x;
  const int b = blk >> 5;
  const int c = blk & 31;
  const int tid = threadIdx.x;
  const int half = tid >> 7;         // t-offset half*32
  const int ch0 = (tid & 127) * 8;

  __shared__ float sHalf0[1024];     // half-0 endsum per channel
  __shared__ float sCarry[1024];     // chunk carry-in per channel

  float a[8];
  *(float4*)&a[0] = *(const float4*)(Adiag + ch0);
  *(float4*)&a[4] = *(const float4*)(Adiag + ch0 + 4);
  float a32[8], aL[8];
#pragma unroll
  for (int j = 0; j < 8; ++j) {
    float t = a[j];
    t *= t; t *= t; t *= t; t *= t; t *= t;  // a^32
    a32[j] = t;
    aL[j] = t * t;                           // a^64
  }

  // local prefix scan over 32 steps, prefixes kept in regs (bf16-packed)
  const size_t base = ((size_t)(b * SEQ + c * SC_LEN + half * 32)) * DIM + ch0;
  ushort8 rv[32];
  float s[8];
#pragma unroll
  for (int j = 0; j < 8; ++j) s[j] = 0.f;
#pragma unroll
  for (int t = 0; t < 32; ++t) {
    ushort8 v = *(const ushort8*)(u + base + (size_t)t * DIM);
#pragma unroll
    for (int j = 0; j < 8; ++j) {
      s[j] = fmaf(a[j], s[j], bf2f(v[j]));
      rv[t][j] = f2bf(s[j]);
    }
  }

  if (half == 0) {
    *(float4*)(sHalf0 + ch0) = *(float4*)&s[0];
    *(float4*)(sHalf0 + ch0 + 4) = *(float4*)&s[4];
  }
  __syncthreads();

  // publish chunk aggregate: agg = s1 + a^32 * h0  (computed by half-1)
  if (half == 1) {
    float* dst = aggbuf + (size_t)blk * 1024 + ch0;
#pragma unroll
    for (int j = 0; j < 8; ++j) dst[j] = fmaf(a32[j], sHalf0[ch0 + j], s[j]);
  }
  __threadfence();
  __syncthreads();
  if (tid == 0)
    __hip_atomic_store(&flags[blk], 1u, __ATOMIC_RELEASE,
                       __HIP_MEMORY_SCOPE_AGENT);

  // lookback (half-0 threads): carry = sum_p agg_p * (a^64)^(c-1-p)
  if (half == 0) {
    float cb[8];
#pragma unroll
    for (int j = 0; j < 8; ++j) cb[j] = 0.f;
    for (int p = 0; p < c; ++p) {
      const int fi = b * 32 + p;
      while (__hip_atomic_load(&flags[fi], __ATOMIC_ACQUIRE,
                               __HIP_MEMORY_SCOPE_AGENT) == 0u)
        __builtin_amdgcn_s_sleep(1);
      const float* src = aggbuf + (size_t)fi * 1024 + ch0;
      float4 g0 = *(const float4*)src;
      float4 g1 = *(const float4*)(src + 4);
      float g[8] = {g0.x, g0.y, g0.z, g0.w, g1.x, g1.y, g1.z, g1.w};
#pragma unroll
      for (int j = 0; j < 8; ++j) cb[j] = fmaf(aL[j], cb[j], g[j]);
    }
    *(float4*)(sCarry + ch0) = *(float4*)&cb[0];
    *(float4*)(sCarry + ch0 + 4) = *(float4*)&cb[4];
  }
  __syncthreads();

  // apply: h_t = r_t + a^(t_local+1) * ce ; half0: ce = C; half1: ce = h0 + a^32*C
  float ce[8], apow[8];
#pragma unroll
  for (int j = 0; j < 8; ++j) {
    float C = sCarry[ch0 + j];
    ce[j] = half ? fmaf(a32[j], C, sHalf0[ch0 + j]) : C;
    apow[j] = a[j];
  }
#pragma unroll
  for (int t = 0; t < 32; ++t) {
    ushort8 o;
#pragma unroll
    for (int j = 0; j < 8; ++j) {
      o[j] = f2bf(fmaf(apow[j], ce[j], bf2f(rv[t][j])));
      apow[j] *= a[j];
    }
    *(ushort8*)(u + base + (size_t)t * DIM) = o;
  }
}

// ---------- GEMM2: y = h . W^T + bias (fp32 out) — round-2 verbatim ----------

__global__ __launch_bounds__(256) void gemm2(
    const unsigned short* __restrict__ A, const unsigned short* __restrict__ B,
    float* __restrict__ C, const float* __restrict__ bias) {
  __shared__ unsigned short smem[16384];
  unsigned short* sA = smem;
  unsigned short* sB = smem + 8192;

  const int tid = threadIdx.x;
  const int wave = tid >> 6, lane = tid & 63;

  const int id = blockIdx.x;
  const int xcd = id & 7, j = id >> 3;
  const int mt = xcd * 16 + (j >> 3);
  const int nt = j & 7;
  const size_t m0 = (size_t)mt * 128;
  const int n0 = nt * 128;

  floatx4 acc[4][4] = {};

  const int srow = wave * 8 + (lane >> 3);
  const int scol = (((lane & 7) ^ ((lane >> 3) & 7)) * 8);
  const unsigned short* gA = A + (m0 + srow) * 1024 + scol;
  const unsigned short* gB = B + ((size_t)n0 + srow) * 1024 + scol;
  unsigned short* lA = sA + wave * 8 * 64;
  unsigned short* lB = sB + wave * 8 * 64;

  const int fr = lane & 15;
  const int frs = fr & 7;
  const int kb = lane >> 4;
  const int wm = (wave & 1) * 64, wn = (wave >> 1) * 64;

  for (int kt = 0; kt < 1024; kt += 64) {
#pragma unroll
    for (int r = 0; r < 4; ++r) {
      gll16(gA + (size_t)r * 32 * 1024 + kt, lA + r * 32 * 64);
      gll16(gB + (size_t)r * 32 * 1024 + kt, lB + r * 32 * 64);
    }
    asm volatile("s_waitcnt vmcnt(0)" ::: "memory");
    __syncthreads();
#pragma unroll
    for (int kk = 0; kk < 64; kk += 32) {
      short8 af[4], bfv[4];
#pragma unroll
      for (int i = 0; i < 4; ++i)
        af[i] = *(const short8*)(sA + (wm + i * 16 + fr) * 64 +
                                 ((((kk >> 3) + kb) ^ frs) * 8));
#pragma unroll
      for (int jj = 0; jj < 4; ++jj)
        bfv[jj] = *(const short8*)(sB + (wn + jj * 16 + fr) * 64 +
                                   ((((kk >> 3) + kb) ^ frs) * 8));
#pragma unroll
      for (int i = 0; i < 4; ++i)
#pragma unroll
        for (int jj = 0; jj < 4; ++jj)
          acc[i][jj] = __builtin_amdgcn_mfma_f32_16x16x32_bf16(
              af[i], bfv[jj], acc[i][jj], 0, 0, 0);
    }
    __syncthreads();
  }

  const int col = lane & 15;
  const int row4 = (lane >> 4) * 4;
#pragma unroll
  for (int i = 0; i < 4; ++i)
#pragma unroll
    for (int jj = 0; jj < 4; ++jj)
#pragma unroll
      for (int r = 0; r < 4; ++r) {
        size_t m = m0 + wm + i * 16 + row4 + r;
        int n = n0 + wn + jj * 16 + col;
        C[m * 1024 + n] = acc[i][jj][r] + bias[n];
      }
}

// ---------- launcher ----------

extern "C" void kernel_launch(void* const* d_in, const int* in_sizes, int n_in,
                              void* d_out, int out_size, void* d_ws,
                              size_t ws_size, hipStream_t stream) {
  const float* x    = (const float*)d_in[0];
  const float* A    = (const float*)d_in[1];
  const float* B    = (const float*)d_in[2];
  const float* W    = (const float*)d_in[3];
  const float* bias = (const float*)d_in[4];

  char* ws = (char*)d_ws;
  unsigned short* ubuf = (unsigned short*)ws;             // 32 MB (u -> h)
  unsigned short* Bb = (unsigned short*)(ws + 33554432);  //  2 MB
  unsigned short* Wb = (unsigned short*)(ws + 35651584);  //  2 MB
  float* aggbuf = (float*)(ws + 37748736);                //  1 MB
  unsigned* flags = (unsigned*)(ws + 38797312);           //  256 flags

  castBW_kernel<<<2 * MN8 / 256, 256, 0, stream>>>(B, W, Bb, Wb, flags);

  gemm1<<<(MTOT / 128) * (DIM / 128), 256, 0, stream>>>(x, Bb, ubuf);

  scan_lb<<<BATCH * SC_NCH, 256, 0, stream>>>(ubuf, A, aggbuf, flags);

  gemm2<<<(MTOT / 128) * (DIM / 128), 256, 0, stream>>>(ubuf, Wb,
                                                        (float*)d_out, bias);
}